// Round 24
// baseline (168.500 us; speedup 1.0000x reference)
//
#include <hip/hip_runtime.h>
#include <hip/hip_bf16.h>
#include <hip/hip_fp16.h>
#include <cstdint>
#include <cstddef>

// ---------------------------------------------------------------------------
// FeatureExtractorGAT, round 22 design (3rd submission; R22/R23 benches were
// infra failures — UnresponsiveContainer — so this has never been measured).
// Single change vs R21 (168 us; gat1_agg_h 46 us @ VALU 73%: with 1 node per
// wave the edge loop runs ~2 iters, so per-block fixed costs - 13.4 KB table
// staging + barrier + h-phase prologue - dominate across 12500 blocks):
//   gat1_agg_h now processes 4 NODES PER WAVE (16 per block, grid 3125):
//   tables staged once per 16 nodes (4x amortization), per-node edge/h
//   phases unchanged in a sequential loop.
// Everything else byte-identical to R21.
// ---------------------------------------------------------------------------

typedef _Float16 half8 __attribute__((ext_vector_type(8)));
typedef float floatx4 __attribute__((ext_vector_type(4)));

constexpr int BSH = 7;            // 128 nodes per bucket
constexpr int MAXBUK = 512;       // supports N <= 65536

__global__ void zero_bcnt(int* __restrict__ bcnt)
{
    bcnt[threadIdx.x] = 0;        // MAXBUK = 512 = blockDim
}

// ---- fused setup: block 0 = prep(w1t,wa2t); [1,1+NW2T) = w2t;
// [A1_0, A1_0+NA1) = a1 (self-computed wa1 in LDS); [H0, ...) = bucket_hist.
__global__ __launch_bounds__(256) void setup_kernel(
    const float* __restrict__ W1,
    const float* __restrict__ as1, const float* __restrict__ ad1,
    const float* __restrict__ W2,
    const float* __restrict__ as2, const float* __restrict__ ad2,
    const float* __restrict__ x, const int* __restrict__ ei,
    int E, int N,
    float4* __restrict__ w1t, float2* __restrict__ wa2t,
    __half* __restrict__ w2t,
    float* __restrict__ a_s1, float* __restrict__ a_d1,
    int* __restrict__ bcnt,
    int NW2T, int NA1)
{
    __shared__ int   lcnt[MAXBUK];
    __shared__ float wa1s[64];
    int b = blockIdx.x;
    int t = threadIdx.x;
    int A1_0 = 1 + NW2T;
    int H0   = A1_0 + NA1;

    if (b == 0) {
        for (int i = t; i < 480; i += 256) {
            float accs = 0.f, accd = 0.f;
            #pragma unroll 4
            for (int c = 0; c < 96; ++c) {
                float w = W2[i * 96 + c];
                accs += w * as2[c];
                accd += w * ad2[c];
            }
            wa2t[i] = make_float2(accs, accd);
            w1t[i]  = make_float4(W1[i], W1[480 + i], W1[960 + i], W1[1440 + i]);
        }
    } else if (b < A1_0) {
        int idx = (b - 1) * 256 + t;
        if (idx < 96 * 480) {
            int n = idx / 480, k = idx - n * 480;
            w2t[idx] = __float2half(W2[k * 96 + n]);
        }
    } else if (b < H0) {
        if (t < 32) {
            int k = t >> 3, h = t & 7;
            float accs = 0.f, accd = 0.f;
            for (int c = 0; c < 60; ++c) {
                float w = W1[k * 480 + h * 60 + c];
                accs += w * as1[h * 60 + c];
                accd += w * ad1[h * 60 + c];
            }
            wa1s[k * 8 + h]      = accs;
            wa1s[32 + k * 8 + h] = accd;
        }
        __syncthreads();
        int n = (b - A1_0) * 256 + t;
        if (n < N) {
            float4 xv = *(const float4*)(x + (size_t)n * 4);
            #pragma unroll
            for (int h = 0; h < 8; ++h) {
                float as = xv.x * wa1s[h] + xv.y * wa1s[8 + h]
                         + xv.z * wa1s[16 + h] + xv.w * wa1s[24 + h];
                float ad = xv.x * wa1s[32 + h] + xv.y * wa1s[40 + h]
                         + xv.z * wa1s[48 + h] + xv.w * wa1s[56 + h];
                a_s1[n * 8 + h] = as;
                a_d1[n * 8 + h] = ad;
            }
        }
    } else {
        int nbuk = (N + 127) >> BSH;
        for (int i = t; i < nbuk; i += 256) lcnt[i] = 0;
        __syncthreads();
        #pragma unroll
        for (int u = 0; u < 8; ++u) {
            int e = (b - H0) * 2048 + u * 256 + t;
            if (e < E + N) {
                int d = (e < E) ? ei[E + e] : (e - E);
                atomicAdd(&lcnt[d >> BSH], 1);
            }
        }
        __syncthreads();
        for (int i = t; i < nbuk; i += 256)
            if (lcnt[i]) atomicAdd(&bcnt[i], lcnt[i]);
    }
}

// ---- CSR build pass 2: scan bucket counts (1 block, 512 thr)
__global__ __launch_bounds__(512) void bucket_scan(const int* __restrict__ bcnt, int nbuk,
                                                   int* __restrict__ boff,
                                                   int* __restrict__ bcursor,
                                                   int* __restrict__ row_ptr, int N)
{
    __shared__ int wsum[8];
    int t = threadIdx.x, lane = t & 63, wid = t >> 6;
    int v = (t < nbuk) ? bcnt[t] : 0;
    int x = v;
    #pragma unroll
    for (int off = 1; off < 64; off <<= 1) {
        int y = __shfl_up(x, off, 64);
        if (lane >= off) x += y;
    }
    if (lane == 63) wsum[wid] = x;
    __syncthreads();
    if (wid == 0) {
        int wv = (lane < 8) ? wsum[lane] : 0;
        #pragma unroll
        for (int off = 1; off < 8; off <<= 1) {
            int y = __shfl_up(wv, off, 64);
            if (lane >= off) wv += y;
        }
        if (lane < 8) wsum[lane] = wv;
    }
    __syncthreads();
    int excl = (wid ? wsum[wid - 1] : 0) + x - v;
    if (t < nbuk) { boff[t] = excl; bcursor[t] = excl; }
    if (t == nbuk - 1) { boff[nbuk] = excl + v; row_ptr[N] = excl + v; }
}

// ---- CSR build pass 3: multisplit (src,dst) pairs into bucket regions.
__global__ __launch_bounds__(256) void multisplit(const int* __restrict__ ei, int E, int N,
                                                  int* __restrict__ bcursor,
                                                  int2* __restrict__ ebuf)
{
    __shared__ int lcnt[MAXBUK];
    __shared__ int lbase[MAXBUK];
    int t = threadIdx.x;
    int nbuk = (N + 127) >> BSH;
    for (int b = t; b < nbuk; b += 256) lcnt[b] = 0;
    __syncthreads();
    constexpr int U = 16;
    int ss[U], dd[U], rk[U];
    bool ok[U];
    #pragma unroll
    for (int u = 0; u < U; ++u) {
        int e = blockIdx.x * (256 * U) + u * 256 + t;
        ok[u] = e < E + N;
        if (ok[u]) {
            if (e < E) { ss[u] = ei[e]; dd[u] = ei[E + e]; } else { ss[u] = dd[u] = e - E; }
            rk[u] = atomicAdd(&lcnt[dd[u] >> BSH], 1);
        }
    }
    __syncthreads();
    for (int b = t; b < nbuk; b += 256)
        lbase[b] = lcnt[b] ? atomicAdd(&bcursor[b], lcnt[b]) : 0;
    __syncthreads();
    #pragma unroll
    for (int u = 0; u < U; ++u)
        if (ok[u]) ebuf[(size_t)lbase[dd[u] >> BSH] + rk[u]] = make_int2(ss[u], dd[u]);
}

// ---- CSR build pass 4: one block per bucket; cursors in LDS; writes
// csr AND csrdst (dst companion, needed by p2_kernel).
__global__ __launch_bounds__(256) void csrfill2(const int2* __restrict__ ebuf,
                                                const int* __restrict__ boff,
                                                int* __restrict__ row_ptr,
                                                int* __restrict__ csr,
                                                int* __restrict__ csrdst, int N)
{
    int b = blockIdx.x;
    int node0 = b << BSH;
    int nnode = N - node0;  if (nnode > 128) nnode = 128;
    int beg = boff[b], end = boff[b + 1];
    __shared__ int hcnt[128], hcur[128];
    __shared__ int wends[4];
    int t = threadIdx.x;
    if (t < 128) hcnt[t] = 0;
    __syncthreads();
    for (int i = beg + t; i < end; i += 256)
        atomicAdd(&hcnt[ebuf[i].y - node0], 1);
    __syncthreads();
    int lane = t & 63, wid = t >> 6;
    int v = (t < 128) ? hcnt[t] : 0;
    int x = v;
    #pragma unroll
    for (int off = 1; off < 64; off <<= 1) {
        int y = __shfl_up(x, off, 64);
        if (lane >= off) x += y;
    }
    if (lane == 63) wends[wid] = x;
    __syncthreads();
    int excl = x - v + ((wid == 1) ? wends[0] : 0);
    if (t < 128) {
        hcur[t] = excl;
        if (t < nnode) row_ptr[node0 + t] = beg + excl;
    }
    __syncthreads();
    for (int i = beg + t; i < end; i += 256) {
        int2 e = ebuf[i];
        int p = atomicAdd(&hcur[e.y - node0], 1);
        csr[(size_t)beg + p]    = e.x;
        csrdst[(size_t)beg + p] = e.y;
    }
}

// ---- GAT layer 1: aggregation + h-phase, fused. Block = 4 waves,
// 4 NODES PER WAVE (16 per block). Tables staged once per block.
// Edge phase: lane = es*8 + h; h-phase: lane l<60 handles cols h*60+l.
__global__ __launch_bounds__(256) void gat1_agg_h(
    const int* __restrict__ row_ptr, const int* __restrict__ csr,
    const float* __restrict__ x,
    const float* __restrict__ a_s1, const float* __restrict__ a_d1,
    const float4* __restrict__ w1t, const float* __restrict__ b1,
    const float2* __restrict__ wa2t,
    __half* __restrict__ h2buf, float* __restrict__ a2s, float* __restrict__ a2d, int N)
{
    __shared__ float4 w1s[480];
    __shared__ float2 wa2s[480];
    __shared__ float  b1s[480];
    __shared__ float  aggL[4][32];
    __shared__ float  ssumL[4][8];
    int t = threadIdx.x;
    for (int i = t; i < 480; i += 256) {
        w1s[i]  = w1t[i];
        wa2s[i] = wa2t[i];
        b1s[i]  = b1[i];
    }
    __syncthreads();   // tables ready (only block-wide barrier)

    int wv   = t >> 6;
    int lane = t & 63;
    int es = lane >> 3;
    int h8 = lane & 7;
    bool act = lane < 60;

    #pragma unroll
    for (int nn = 0; nn < 4; ++nn) {
        int node = blockIdx.x * 16 + wv * 4 + nn;
        if (node >= N) break;

        // ---- edge phase: lane = es*8 + h ----
        float ax = 0.f, ay = 0.f, az = 0.f, aw = 0.f, sv = 0.f;
        {
            float adh = a_d1[(size_t)node * 8 + h8];
            int beg = row_ptr[node], end = row_ptr[node + 1];
            constexpr int U = 2;                 // 16 edges per iteration
            for (int base = beg; base < end; base += 8 * U) {
                int   src[U];
                float msk[U];
                #pragma unroll
                for (int u = 0; u < U; ++u) {
                    int tt = base + u * 8 + es;
                    msk[u] = (tt < end) ? 1.f : 0.f;
                    src[u] = csr[tt < end ? tt : (end - 1)];
                }
                float4 xv[U];
                float  asv[U];
                #pragma unroll
                for (int u = 0; u < U; ++u) xv[u] = *(const float4*)(x + (size_t)src[u] * 4);
                #pragma unroll
                for (int u = 0; u < U; ++u) asv[u] = a_s1[(size_t)src[u] * 8 + h8];
                #pragma unroll
                for (int u = 0; u < U; ++u) {
                    float ev = asv[u] + adh;
                    ev = fmaxf(ev, 0.2f * ev);
                    float p = __expf(ev) * msk[u];
                    sv += p;
                    ax += p * xv[u].x;
                    ay += p * xv[u].y;
                    az += p * xv[u].z;
                    aw += p * xv[u].w;
                }
            }
            #pragma unroll
            for (int off = 8; off <= 32; off <<= 1) {
                ax += __shfl_xor(ax, off);
                ay += __shfl_xor(ay, off);
                az += __shfl_xor(az, off);
                aw += __shfl_xor(aw, off);
                sv += __shfl_xor(sv, off);
            }
            if (lane < 8) {                       // es == 0 holds the totals
                aggL[wv][h8 * 4 + 0] = ax;
                aggL[wv][h8 * 4 + 1] = ay;
                aggL[wv][h8 * 4 + 2] = az;
                aggL[wv][h8 * 4 + 3] = aw;
                ssumL[wv][h8] = sv;
            }
        }
        // same-wave LDS write->read: ordered by lgkmcnt, no barrier needed

        // ---- h phase ----
        float psrc = 0.f, pdst = 0.f;
        #pragma unroll
        for (int h = 0; h < 8; ++h) {
            float ag0 = aggL[wv][h * 4 + 0];
            float ag1 = aggL[wv][h * 4 + 1];
            float ag2 = aggL[wv][h * 4 + 2];
            float ag3 = aggL[wv][h * 4 + 3];
            float inv = 1.f / (ssumL[wv][h] + 1e-16f);
            if (act) {
                int col = h * 60 + lane;
                float4 w  = w1s[col];
                float raw = ag0 * w.x + ag1 * w.y + ag2 * w.z + ag3 * w.w;
                float v   = raw * inv + b1s[col];
                float o   = v > 0.f ? v : (__expf(v) - 1.f);
                h2buf[(size_t)node * 480 + col] = __float2half(o);
                float2 wz = wa2s[col];
                psrc += o * wz.x;
                pdst += o * wz.y;
            }
        }
        #pragma unroll
        for (int off = 32; off; off >>= 1) {
            psrc += __shfl_xor(psrc, off);
            pdst += __shfl_xor(pdst, off);
        }
        if (lane == 0) { a2s[node] = psrc; a2d[node] = pdst; }
    }
}

// ---- p2: p[e] = exp(leaky(a_s2[csr[e]] + a_d2[csrdst[e]])), edge-parallel
__global__ __launch_bounds__(256) void p2_kernel(
    const int* __restrict__ csr, const int* __restrict__ csrdst,
    const float* __restrict__ a_s2, const float* __restrict__ a_d2,
    float* __restrict__ pbuf2, int EP)
{
    int i = (blockIdx.x * 256 + threadIdx.x) * 4;
    if (i + 3 < EP) {
        int4 s4 = *(const int4*)(csr + i);
        int4 d4 = *(const int4*)(csrdst + i);
        float e0 = a_s2[s4.x] + a_d2[d4.x];
        float e1 = a_s2[s4.y] + a_d2[d4.y];
        float e2 = a_s2[s4.z] + a_d2[d4.z];
        float e3 = a_s2[s4.w] + a_d2[d4.w];
        float4 o;
        o.x = __expf(fmaxf(e0, 0.2f * e0));
        o.y = __expf(fmaxf(e1, 0.2f * e1));
        o.z = __expf(fmaxf(e2, 0.2f * e2));
        o.w = __expf(fmaxf(e3, 0.2f * e3));
        *(float4*)(pbuf2 + i) = o;
    } else {
        for (int u = 0; u < 4; ++u) {
            int e = i + u;
            if (e < EP) {
                float ev = a_s2[csr[e]] + a_d2[csrdst[e]];
                pbuf2[e] = __expf(fmaxf(ev, 0.2f * ev));
            }
        }
    }
}

// ---- xh2h[N,96] = h2[N,480] @ W2[480,96] via MFMA fp16 (f32 accum).
__global__ __launch_bounds__(256) void gemm2_mfma(
    const __half* __restrict__ h2, const __half* __restrict__ w2t,
    __half* __restrict__ xh2h, int N)
{
    int wave = threadIdx.x >> 6;
    int lane = threadIdx.x & 63;
    int m0 = blockIdx.x * 64 + wave * 16;
    int ra   = lane & 15;
    int kgrp = lane >> 4;
    int m = m0 + ra;  if (m > N - 1) m = N - 1;   // clamp: OOB rows duplicate N-1

    floatx4 acc[6];
    #pragma unroll
    for (int n = 0; n < 6; ++n) acc[n] = (floatx4){0.f, 0.f, 0.f, 0.f};

    const _Float16* arow = (const _Float16*)(h2 + (size_t)m * 480);
    const _Float16* wt   = (const _Float16*)w2t;
    for (int k0 = 0; k0 < 480; k0 += 32) {
        half8 af = *(const half8*)(arow + k0 + kgrp * 8);
        #pragma unroll
        for (int n = 0; n < 6; ++n) {
            half8 bf = *(const half8*)(wt + (size_t)(n * 16 + ra) * 480 + k0 + kgrp * 8);
            acc[n] = __builtin_amdgcn_mfma_f32_16x16x32_f16(af, bf, acc[n], 0, 0, 0);
        }
    }
    #pragma unroll
    for (int n = 0; n < 6; ++n) {
        int c = n * 16 + ra;
        #pragma unroll
        for (int j = 0; j < 4; ++j) {
            int r = m0 + kgrp * 4 + j;
            if (r < N) xh2h[(size_t)r * 96 + c] = __float2half(acc[n][j]);
        }
    }
}

// ---- GAT layer 2: wave/node; contiguous s_load batches of csr + pbuf2
// (independent), gather + cvt + 2 FMA per edge; U=16.
__global__ __launch_bounds__(256) void gat2_fused(
    const int* __restrict__ row_ptr, const int* __restrict__ csr,
    const float* __restrict__ pbuf2,
    const __half* __restrict__ xh2h, const float* __restrict__ b2,
    float* __restrict__ out, int N)
{
    int gid = blockIdx.x * blockDim.x + threadIdx.x;
    int node = gid >> 6;
    if (node >= N) return;
    int lane = threadIdx.x & 63;
    bool act = lane < 48;
    float s = 0.f, ax = 0.f, ay = 0.f;
    int beg = __builtin_amdgcn_readfirstlane(row_ptr[node]);
    int end = __builtin_amdgcn_readfirstlane(row_ptr[node + 1]);
    constexpr int U = 16;
    for (int e0 = beg; e0 < end; e0 += U) {
        int   srcs[U];
        float pv[U];
        #pragma unroll
        for (int u = 0; u < U; ++u) {
            int t = e0 + u;  if (t > end - 1) t = end - 1;      // scalar clamp
            srcs[u] = __builtin_amdgcn_readfirstlane(csr[t]);
            float pr = __uint_as_float(
                __builtin_amdgcn_readfirstlane(__float_as_uint(pbuf2[t])));
            pv[u] = (e0 + u < end) ? pr : 0.f;                  // uniform select
        }
        __half2 gv[U];
        if (act) {
            #pragma unroll
            for (int u = 0; u < U; ++u)
                gv[u] = ((const __half2*)(xh2h + (size_t)srcs[u] * 96))[lane];
        }
        #pragma unroll
        for (int u = 0; u < U; ++u) {
            s += pv[u];
            if (act) {
                float2 fg = __half22float2(gv[u]);
                ax += pv[u] * fg.x;
                ay += pv[u] * fg.y;
            }
        }
    }
    float inv = 1.f / (s + 1e-16f);
    if (act) {
        out[(size_t)node * 96 + 2 * lane]     = ax * inv + b2[2 * lane];
        out[(size_t)node * 96 + 2 * lane + 1] = ay * inv + b2[2 * lane + 1];
    }
}

extern "C" void kernel_launch(void* const* d_in, const int* in_sizes, int n_in,
                              void* d_out, int out_size, void* d_ws, size_t ws_size,
                              hipStream_t stream)
{
    const float* x   = (const float*)d_in[0];
    const int*   ei  = (const int*)  d_in[1];
    const float* W1  = (const float*)d_in[2];
    const float* as1 = (const float*)d_in[3];
    const float* ad1 = (const float*)d_in[4];
    const float* b1  = (const float*)d_in[5];
    const float* W2  = (const float*)d_in[6];
    const float* as2 = (const float*)d_in[7];
    const float* ad2 = (const float*)d_in[8];
    const float* b2  = (const float*)d_in[9];
    float* out = (float*)d_out;

    int N  = in_sizes[0] / 4;   // 50000
    int E  = in_sizes[1] / 2;   // 800000
    int EP = E + N;
    int NBUK  = (N + 127) >> BSH;           // 391
    int NW2T  = (96 * 480 + 255) / 256;     // 180
    int NA1   = (N + 255) / 256;            // 196
    int NBK_H = (EP + 2047) / 2048;         // 416
    int NBK_M = (EP + 4095) / 4096;         // multisplit blocks (U=16)
    int NSETUP = 1 + NW2T + NA1 + NBK_H;

    float* f = (float*)d_ws;
    float* a_s1  = f;  f += (size_t)N * 8;
    float* a_d1  = f;  f += (size_t)N * 8;
    float* a_s2  = f;  f += N;
    float* a_d2  = f;  f += N;
    float4* w1t  = (float4*)f;  f += 480 * 4;
    float2* wa2t = (float2*)f;  f += 480 * 2;
    __half* h2buf = (__half*)f;
    __half* hp   = h2buf + (size_t)N * 480;
    __half* xh2h = hp;   hp += (size_t)N * 96;
    __half* w2t  = hp;   hp += 96 * 480;
    int2* ebuf   = (int2*)hp;
    int* ip      = (int*)(ebuf + EP);
    int* row_ptr = ip;  ip += N + 1;
    int* bcnt    = ip;  ip += MAXBUK;
    int* boff    = ip;  ip += MAXBUK + 1;
    int* bcursor = ip;  ip += MAXBUK;
    int* csr     = ip;  ip += EP;
    int* csrdst  = ip;  ip += EP;
    float* pbuf2 = (float*)ip;  ip += EP;

    size_t needed = (size_t)((char*)ip - (char*)d_ws);
    if (needed > ws_size) return;  // loud failure if scratch too small

    zero_bcnt<<<1, MAXBUK, 0, stream>>>(bcnt);
    setup_kernel<<<NSETUP, 256, 0, stream>>>(
        W1, as1, ad1, W2, as2, ad2, x, ei, E, N,
        w1t, wa2t, w2t, a_s1, a_d1, bcnt, NW2T, NA1);
    bucket_scan<<<1, 512, 0, stream>>>(bcnt, NBUK, boff, bcursor, row_ptr, N);
    multisplit<<<NBK_M, 256, 0, stream>>>(ei, E, N, bcursor, ebuf);
    csrfill2<<<NBUK, 256, 0, stream>>>(ebuf, boff, row_ptr, csr, csrdst, N);
    gat1_agg_h<<<(N + 15) / 16, 256, 0, stream>>>(
        row_ptr, csr, x, a_s1, a_d1, w1t, b1, wa2t, h2buf, a_s2, a_d2, N);
    p2_kernel<<<(EP + 1023) / 1024, 256, 0, stream>>>(
        csr, csrdst, a_s2, a_d2, pbuf2, EP);
    gemm2_mfma<<<(N + 63) / 64, 256, 0, stream>>>(h2buf, w2t, xh2h, N);
    gat2_fused<<<(N * 64 + 255) / 256, 256, 0, stream>>>(
        row_ptr, csr, pbuf2, xh2h, b2, out, N);
}

// Round 27
// 164.033 us; speedup vs baseline: 1.0272x; 1.0272x over previous
//
#include <hip/hip_runtime.h>
#include <hip/hip_bf16.h>
#include <hip/hip_fp16.h>
#include <cstdint>
#include <cstddef>

// ---------------------------------------------------------------------------
// FeatureExtractorGAT, round 25 design (3rd submission; R25/R26 benches were
// infra failures — UnresponsiveContainer — so this has never been measured).
// R24 measured the 4-nodes/wave gat1_agg_h as NEUTRAL (168.5 vs 168.0):
// VALU 73->62% (staging amortized) but occupancy 66->54% (4x fewer waves,
// tail effect) - net zero. Changes vs R24:
//  - gat1_agg_h reverted to R21's 1-node-per-wave form (equal-best, more
//    waves for latency hiding, simpler).
//  - gemm2_mfma + p2_kernel (independent after gat1_agg_h) fused into one
//    tail_kernel dispatch via blockIdx range: one less launch gap.
// Everything else byte-identical to R24.
// ---------------------------------------------------------------------------

typedef _Float16 half8 __attribute__((ext_vector_type(8)));
typedef float floatx4 __attribute__((ext_vector_type(4)));

constexpr int BSH = 7;            // 128 nodes per bucket
constexpr int MAXBUK = 512;       // supports N <= 65536

__global__ void zero_bcnt(int* __restrict__ bcnt)
{
    bcnt[threadIdx.x] = 0;        // MAXBUK = 512 = blockDim
}

// ---- fused setup: block 0 = prep(w1t,wa2t); [1,1+NW2T) = w2t;
// [A1_0, A1_0+NA1) = a1 (self-computed wa1 in LDS); [H0, ...) = bucket_hist.
__global__ __launch_bounds__(256) void setup_kernel(
    const float* __restrict__ W1,
    const float* __restrict__ as1, const float* __restrict__ ad1,
    const float* __restrict__ W2,
    const float* __restrict__ as2, const float* __restrict__ ad2,
    const float* __restrict__ x, const int* __restrict__ ei,
    int E, int N,
    float4* __restrict__ w1t, float2* __restrict__ wa2t,
    __half* __restrict__ w2t,
    float* __restrict__ a_s1, float* __restrict__ a_d1,
    int* __restrict__ bcnt,
    int NW2T, int NA1)
{
    __shared__ int   lcnt[MAXBUK];
    __shared__ float wa1s[64];
    int b = blockIdx.x;
    int t = threadIdx.x;
    int A1_0 = 1 + NW2T;
    int H0   = A1_0 + NA1;

    if (b == 0) {
        for (int i = t; i < 480; i += 256) {
            float accs = 0.f, accd = 0.f;
            #pragma unroll 4
            for (int c = 0; c < 96; ++c) {
                float w = W2[i * 96 + c];
                accs += w * as2[c];
                accd += w * ad2[c];
            }
            wa2t[i] = make_float2(accs, accd);
            w1t[i]  = make_float4(W1[i], W1[480 + i], W1[960 + i], W1[1440 + i]);
        }
    } else if (b < A1_0) {
        int idx = (b - 1) * 256 + t;
        if (idx < 96 * 480) {
            int n = idx / 480, k = idx - n * 480;
            w2t[idx] = __float2half(W2[k * 96 + n]);
        }
    } else if (b < H0) {
        if (t < 32) {
            int k = t >> 3, h = t & 7;
            float accs = 0.f, accd = 0.f;
            for (int c = 0; c < 60; ++c) {
                float w = W1[k * 480 + h * 60 + c];
                accs += w * as1[h * 60 + c];
                accd += w * ad1[h * 60 + c];
            }
            wa1s[k * 8 + h]      = accs;
            wa1s[32 + k * 8 + h] = accd;
        }
        __syncthreads();
        int n = (b - A1_0) * 256 + t;
        if (n < N) {
            float4 xv = *(const float4*)(x + (size_t)n * 4);
            #pragma unroll
            for (int h = 0; h < 8; ++h) {
                float as = xv.x * wa1s[h] + xv.y * wa1s[8 + h]
                         + xv.z * wa1s[16 + h] + xv.w * wa1s[24 + h];
                float ad = xv.x * wa1s[32 + h] + xv.y * wa1s[40 + h]
                         + xv.z * wa1s[48 + h] + xv.w * wa1s[56 + h];
                a_s1[n * 8 + h] = as;
                a_d1[n * 8 + h] = ad;
            }
        }
    } else {
        int nbuk = (N + 127) >> BSH;
        for (int i = t; i < nbuk; i += 256) lcnt[i] = 0;
        __syncthreads();
        #pragma unroll
        for (int u = 0; u < 8; ++u) {
            int e = (b - H0) * 2048 + u * 256 + t;
            if (e < E + N) {
                int d = (e < E) ? ei[E + e] : (e - E);
                atomicAdd(&lcnt[d >> BSH], 1);
            }
        }
        __syncthreads();
        for (int i = t; i < nbuk; i += 256)
            if (lcnt[i]) atomicAdd(&bcnt[i], lcnt[i]);
    }
}

// ---- CSR build pass 2: scan bucket counts (1 block, 512 thr)
__global__ __launch_bounds__(512) void bucket_scan(const int* __restrict__ bcnt, int nbuk,
                                                   int* __restrict__ boff,
                                                   int* __restrict__ bcursor,
                                                   int* __restrict__ row_ptr, int N)
{
    __shared__ int wsum[8];
    int t = threadIdx.x, lane = t & 63, wid = t >> 6;
    int v = (t < nbuk) ? bcnt[t] : 0;
    int x = v;
    #pragma unroll
    for (int off = 1; off < 64; off <<= 1) {
        int y = __shfl_up(x, off, 64);
        if (lane >= off) x += y;
    }
    if (lane == 63) wsum[wid] = x;
    __syncthreads();
    if (wid == 0) {
        int wv = (lane < 8) ? wsum[lane] : 0;
        #pragma unroll
        for (int off = 1; off < 8; off <<= 1) {
            int y = __shfl_up(wv, off, 64);
            if (lane >= off) wv += y;
        }
        if (lane < 8) wsum[lane] = wv;
    }
    __syncthreads();
    int excl = (wid ? wsum[wid - 1] : 0) + x - v;
    if (t < nbuk) { boff[t] = excl; bcursor[t] = excl; }
    if (t == nbuk - 1) { boff[nbuk] = excl + v; row_ptr[N] = excl + v; }
}

// ---- CSR build pass 3: multisplit (src,dst) pairs into bucket regions.
__global__ __launch_bounds__(256) void multisplit(const int* __restrict__ ei, int E, int N,
                                                  int* __restrict__ bcursor,
                                                  int2* __restrict__ ebuf)
{
    __shared__ int lcnt[MAXBUK];
    __shared__ int lbase[MAXBUK];
    int t = threadIdx.x;
    int nbuk = (N + 127) >> BSH;
    for (int b = t; b < nbuk; b += 256) lcnt[b] = 0;
    __syncthreads();
    constexpr int U = 16;
    int ss[U], dd[U], rk[U];
    bool ok[U];
    #pragma unroll
    for (int u = 0; u < U; ++u) {
        int e = blockIdx.x * (256 * U) + u * 256 + t;
        ok[u] = e < E + N;
        if (ok[u]) {
            if (e < E) { ss[u] = ei[e]; dd[u] = ei[E + e]; } else { ss[u] = dd[u] = e - E; }
            rk[u] = atomicAdd(&lcnt[dd[u] >> BSH], 1);
        }
    }
    __syncthreads();
    for (int b = t; b < nbuk; b += 256)
        lbase[b] = lcnt[b] ? atomicAdd(&bcursor[b], lcnt[b]) : 0;
    __syncthreads();
    #pragma unroll
    for (int u = 0; u < U; ++u)
        if (ok[u]) ebuf[(size_t)lbase[dd[u] >> BSH] + rk[u]] = make_int2(ss[u], dd[u]);
}

// ---- CSR build pass 4: one block per bucket; cursors in LDS; writes
// csr AND csrdst (dst companion, needed by the p2 phase).
__global__ __launch_bounds__(256) void csrfill2(const int2* __restrict__ ebuf,
                                                const int* __restrict__ boff,
                                                int* __restrict__ row_ptr,
                                                int* __restrict__ csr,
                                                int* __restrict__ csrdst, int N)
{
    int b = blockIdx.x;
    int node0 = b << BSH;
    int nnode = N - node0;  if (nnode > 128) nnode = 128;
    int beg = boff[b], end = boff[b + 1];
    __shared__ int hcnt[128], hcur[128];
    __shared__ int wends[4];
    int t = threadIdx.x;
    if (t < 128) hcnt[t] = 0;
    __syncthreads();
    for (int i = beg + t; i < end; i += 256)
        atomicAdd(&hcnt[ebuf[i].y - node0], 1);
    __syncthreads();
    int lane = t & 63, wid = t >> 6;
    int v = (t < 128) ? hcnt[t] : 0;
    int x = v;
    #pragma unroll
    for (int off = 1; off < 64; off <<= 1) {
        int y = __shfl_up(x, off, 64);
        if (lane >= off) x += y;
    }
    if (lane == 63) wends[wid] = x;
    __syncthreads();
    int excl = x - v + ((wid == 1) ? wends[0] : 0);
    if (t < 128) {
        hcur[t] = excl;
        if (t < nnode) row_ptr[node0 + t] = beg + excl;
    }
    __syncthreads();
    for (int i = beg + t; i < end; i += 256) {
        int2 e = ebuf[i];
        int p = atomicAdd(&hcur[e.y - node0], 1);
        csr[(size_t)beg + p]    = e.x;
        csrdst[(size_t)beg + p] = e.y;
    }
}

// ---- GAT layer 1: aggregation + h-phase, fused (R21 form: 1 node/wave).
// Block = 4 waves = 4 nodes. Tables staged once per block.
// Edge phase: lane = es*8 + h; h-phase: lane l<60 handles cols h*60+l.
__global__ __launch_bounds__(256) void gat1_agg_h(
    const int* __restrict__ row_ptr, const int* __restrict__ csr,
    const float* __restrict__ x,
    const float* __restrict__ a_s1, const float* __restrict__ a_d1,
    const float4* __restrict__ w1t, const float* __restrict__ b1,
    const float2* __restrict__ wa2t,
    __half* __restrict__ h2buf, float* __restrict__ a2s, float* __restrict__ a2d, int N)
{
    __shared__ float4 w1s[480];
    __shared__ float2 wa2s[480];
    __shared__ float  b1s[480];
    __shared__ float  aggL[4][32];
    __shared__ float  ssumL[4][8];
    int t = threadIdx.x;
    for (int i = t; i < 480; i += 256) {
        w1s[i]  = w1t[i];
        wa2s[i] = wa2t[i];
        b1s[i]  = b1[i];
    }
    __syncthreads();   // tables ready

    int wv   = t >> 6;
    int node = blockIdx.x * 4 + wv;
    if (node >= N) return;
    int lane = t & 63;

    // ---- edge phase: lane = es*8 + h ----
    {
        int es = lane >> 3;
        int h  = lane & 7;
        float adh = a_d1[(size_t)node * 8 + h];
        float ax = 0.f, ay = 0.f, az = 0.f, aw = 0.f, sv = 0.f;
        int beg = row_ptr[node], end = row_ptr[node + 1];
        constexpr int U = 2;                 // 16 edges per iteration
        for (int base = beg; base < end; base += 8 * U) {
            int   src[U];
            float msk[U];
            #pragma unroll
            for (int u = 0; u < U; ++u) {
                int tt = base + u * 8 + es;
                msk[u] = (tt < end) ? 1.f : 0.f;
                src[u] = csr[tt < end ? tt : (end - 1)];
            }
            float4 xv[U];
            float  asv[U];
            #pragma unroll
            for (int u = 0; u < U; ++u) xv[u] = *(const float4*)(x + (size_t)src[u] * 4);
            #pragma unroll
            for (int u = 0; u < U; ++u) asv[u] = a_s1[(size_t)src[u] * 8 + h];
            #pragma unroll
            for (int u = 0; u < U; ++u) {
                float ev = asv[u] + adh;
                ev = fmaxf(ev, 0.2f * ev);
                float p = __expf(ev) * msk[u];
                sv += p;
                ax += p * xv[u].x;
                ay += p * xv[u].y;
                az += p * xv[u].z;
                aw += p * xv[u].w;
            }
        }
        #pragma unroll
        for (int off = 8; off <= 32; off <<= 1) {
            ax += __shfl_xor(ax, off);
            ay += __shfl_xor(ay, off);
            az += __shfl_xor(az, off);
            aw += __shfl_xor(aw, off);
            sv += __shfl_xor(sv, off);
        }
        if (lane < 8) {                       // es == 0 holds the totals
            aggL[wv][h * 4 + 0] = ax;
            aggL[wv][h * 4 + 1] = ay;
            aggL[wv][h * 4 + 2] = az;
            aggL[wv][h * 4 + 3] = aw;
            ssumL[wv][h] = sv;
        }
    }
    // same-wave LDS write->read: ordered by lgkmcnt, no barrier needed

    // ---- h phase ----
    bool act = lane < 60;
    float psrc = 0.f, pdst = 0.f;
    #pragma unroll
    for (int h = 0; h < 8; ++h) {
        float ag0 = aggL[wv][h * 4 + 0];
        float ag1 = aggL[wv][h * 4 + 1];
        float ag2 = aggL[wv][h * 4 + 2];
        float ag3 = aggL[wv][h * 4 + 3];
        float inv = 1.f / (ssumL[wv][h] + 1e-16f);
        if (act) {
            int col = h * 60 + lane;
            float4 w  = w1s[col];
            float raw = ag0 * w.x + ag1 * w.y + ag2 * w.z + ag3 * w.w;
            float v   = raw * inv + b1s[col];
            float o   = v > 0.f ? v : (__expf(v) - 1.f);
            h2buf[(size_t)node * 480 + col] = __float2half(o);
            float2 wz = wa2s[col];
            psrc += o * wz.x;
            pdst += o * wz.y;
        }
    }
    #pragma unroll
    for (int off = 32; off; off >>= 1) {
        psrc += __shfl_xor(psrc, off);
        pdst += __shfl_xor(pdst, off);
    }
    if (lane == 0) { a2s[node] = psrc; a2d[node] = pdst; }
}

// ---- tail: blockIdx < NG2 -> gemm2_mfma body; else -> p2 body.
// (independent work, fused into one dispatch to drop a launch gap)
__global__ __launch_bounds__(256) void tail_kernel(
    const __half* __restrict__ h2, const __half* __restrict__ w2t,
    __half* __restrict__ xh2h,
    const int* __restrict__ csr, const int* __restrict__ csrdst,
    const float* __restrict__ a_s2, const float* __restrict__ a_d2,
    float* __restrict__ pbuf2, int N, int EP, int NG2)
{
    if ((int)blockIdx.x < NG2) {
        // ---- gemm2: xh2h[N,96] = h2[N,480] @ W2t via MFMA fp16 (f32 accum)
        int wave = threadIdx.x >> 6;
        int lane = threadIdx.x & 63;
        int m0 = blockIdx.x * 64 + wave * 16;
        int ra   = lane & 15;
        int kgrp = lane >> 4;
        int m = m0 + ra;  if (m > N - 1) m = N - 1;   // clamp

        floatx4 acc[6];
        #pragma unroll
        for (int n = 0; n < 6; ++n) acc[n] = (floatx4){0.f, 0.f, 0.f, 0.f};

        const _Float16* arow = (const _Float16*)(h2 + (size_t)m * 480);
        const _Float16* wt   = (const _Float16*)w2t;
        for (int k0 = 0; k0 < 480; k0 += 32) {
            half8 af = *(const half8*)(arow + k0 + kgrp * 8);
            #pragma unroll
            for (int n = 0; n < 6; ++n) {
                half8 bf = *(const half8*)(wt + (size_t)(n * 16 + ra) * 480 + k0 + kgrp * 8);
                acc[n] = __builtin_amdgcn_mfma_f32_16x16x32_f16(af, bf, acc[n], 0, 0, 0);
            }
        }
        #pragma unroll
        for (int n = 0; n < 6; ++n) {
            int c = n * 16 + ra;
            #pragma unroll
            for (int j = 0; j < 4; ++j) {
                int r = m0 + kgrp * 4 + j;
                if (r < N) xh2h[(size_t)r * 96 + c] = __float2half(acc[n][j]);
            }
        }
    } else {
        // ---- p2: p[e] = exp(leaky(a_s2[csr[e]] + a_d2[csrdst[e]]))
        int i = ((blockIdx.x - NG2) * 256 + threadIdx.x) * 4;
        if (i + 3 < EP) {
            int4 s4 = *(const int4*)(csr + i);
            int4 d4 = *(const int4*)(csrdst + i);
            float e0 = a_s2[s4.x] + a_d2[d4.x];
            float e1 = a_s2[s4.y] + a_d2[d4.y];
            float e2 = a_s2[s4.z] + a_d2[d4.z];
            float e3 = a_s2[s4.w] + a_d2[d4.w];
            float4 o;
            o.x = __expf(fmaxf(e0, 0.2f * e0));
            o.y = __expf(fmaxf(e1, 0.2f * e1));
            o.z = __expf(fmaxf(e2, 0.2f * e2));
            o.w = __expf(fmaxf(e3, 0.2f * e3));
            *(float4*)(pbuf2 + i) = o;
        } else {
            for (int u = 0; u < 4; ++u) {
                int e = i + u;
                if (e < EP) {
                    float ev = a_s2[csr[e]] + a_d2[csrdst[e]];
                    pbuf2[e] = __expf(fmaxf(ev, 0.2f * ev));
                }
            }
        }
    }
}

// ---- GAT layer 2: wave/node; contiguous s_load batches of csr + pbuf2
// (independent), gather + cvt + 2 FMA per edge; U=16.
__global__ __launch_bounds__(256) void gat2_fused(
    const int* __restrict__ row_ptr, const int* __restrict__ csr,
    const float* __restrict__ pbuf2,
    const __half* __restrict__ xh2h, const float* __restrict__ b2,
    float* __restrict__ out, int N)
{
    int gid = blockIdx.x * blockDim.x + threadIdx.x;
    int node = gid >> 6;
    if (node >= N) return;
    int lane = threadIdx.x & 63;
    bool act = lane < 48;
    float s = 0.f, ax = 0.f, ay = 0.f;
    int beg = __builtin_amdgcn_readfirstlane(row_ptr[node]);
    int end = __builtin_amdgcn_readfirstlane(row_ptr[node + 1]);
    constexpr int U = 16;
    for (int e0 = beg; e0 < end; e0 += U) {
        int   srcs[U];
        float pv[U];
        #pragma unroll
        for (int u = 0; u < U; ++u) {
            int t = e0 + u;  if (t > end - 1) t = end - 1;      // scalar clamp
            srcs[u] = __builtin_amdgcn_readfirstlane(csr[t]);
            float pr = __uint_as_float(
                __builtin_amdgcn_readfirstlane(__float_as_uint(pbuf2[t])));
            pv[u] = (e0 + u < end) ? pr : 0.f;                  // uniform select
        }
        __half2 gv[U];
        if (act) {
            #pragma unroll
            for (int u = 0; u < U; ++u)
                gv[u] = ((const __half2*)(xh2h + (size_t)srcs[u] * 96))[lane];
        }
        #pragma unroll
        for (int u = 0; u < U; ++u) {
            s += pv[u];
            if (act) {
                float2 fg = __half22float2(gv[u]);
                ax += pv[u] * fg.x;
                ay += pv[u] * fg.y;
            }
        }
    }
    float inv = 1.f / (s + 1e-16f);
    if (act) {
        out[(size_t)node * 96 + 2 * lane]     = ax * inv + b2[2 * lane];
        out[(size_t)node * 96 + 2 * lane + 1] = ay * inv + b2[2 * lane + 1];
    }
}

extern "C" void kernel_launch(void* const* d_in, const int* in_sizes, int n_in,
                              void* d_out, int out_size, void* d_ws, size_t ws_size,
                              hipStream_t stream)
{
    const float* x   = (const float*)d_in[0];
    const int*   ei  = (const int*)  d_in[1];
    const float* W1  = (const float*)d_in[2];
    const float* as1 = (const float*)d_in[3];
    const float* ad1 = (const float*)d_in[4];
    const float* b1  = (const float*)d_in[5];
    const float* W2  = (const float*)d_in[6];
    const float* as2 = (const float*)d_in[7];
    const float* ad2 = (const float*)d_in[8];
    const float* b2  = (const float*)d_in[9];
    float* out = (float*)d_out;

    int N  = in_sizes[0] / 4;   // 50000
    int E  = in_sizes[1] / 2;   // 800000
    int EP = E + N;
    int NBUK  = (N + 127) >> BSH;           // 391
    int NW2T  = (96 * 480 + 255) / 256;     // 180
    int NA1   = (N + 255) / 256;            // 196
    int NBK_H = (EP + 2047) / 2048;         // 416
    int NBK_M = (EP + 4095) / 4096;         // multisplit blocks (U=16)
    int NSETUP = 1 + NW2T + NA1 + NBK_H;
    int NG2   = (N + 63) / 64;              // gemm2 blocks
    int NP2   = (EP + 1023) / 1024;         // p2 blocks

    float* f = (float*)d_ws;
    float* a_s1  = f;  f += (size_t)N * 8;
    float* a_d1  = f;  f += (size_t)N * 8;
    float* a_s2  = f;  f += N;
    float* a_d2  = f;  f += N;
    float4* w1t  = (float4*)f;  f += 480 * 4;
    float2* wa2t = (float2*)f;  f += 480 * 2;
    __half* h2buf = (__half*)f;
    __half* hp   = h2buf + (size_t)N * 480;
    __half* xh2h = hp;   hp += (size_t)N * 96;
    __half* w2t  = hp;   hp += 96 * 480;
    int2* ebuf   = (int2*)hp;
    int* ip      = (int*)(ebuf + EP);
    int* row_ptr = ip;  ip += N + 1;
    int* bcnt    = ip;  ip += MAXBUK;
    int* boff    = ip;  ip += MAXBUK + 1;
    int* bcursor = ip;  ip += MAXBUK;
    int* csr     = ip;  ip += EP;
    int* csrdst  = ip;  ip += EP;
    float* pbuf2 = (float*)ip;  ip += EP;

    size_t needed = (size_t)((char*)ip - (char*)d_ws);
    if (needed > ws_size) return;  // loud failure if scratch too small

    zero_bcnt<<<1, MAXBUK, 0, stream>>>(bcnt);
    setup_kernel<<<NSETUP, 256, 0, stream>>>(
        W1, as1, ad1, W2, as2, ad2, x, ei, E, N,
        w1t, wa2t, w2t, a_s1, a_d1, bcnt, NW2T, NA1);
    bucket_scan<<<1, 512, 0, stream>>>(bcnt, NBUK, boff, bcursor, row_ptr, N);
    multisplit<<<NBK_M, 256, 0, stream>>>(ei, E, N, bcursor, ebuf);
    csrfill2<<<NBUK, 256, 0, stream>>>(ebuf, boff, row_ptr, csr, csrdst, N);
    gat1_agg_h<<<(N + 3) / 4, 256, 0, stream>>>(
        row_ptr, csr, x, a_s1, a_d1, w1t, b1, wa2t, h2buf, a_s2, a_d2, N);
    tail_kernel<<<NG2 + NP2, 256, 0, stream>>>(
        h2buf, w2t, xh2h, csr, csrdst, a_s2, a_d2, pbuf2, N, EP, NG2);
    gat2_fused<<<(N * 64 + 255) / 256, 256, 0, stream>>>(
        row_ptr, csr, pbuf2, xh2h, b2, out, N);
}

// Round 28
// 162.544 us; speedup vs baseline: 1.0366x; 1.0092x over previous
//
#include <hip/hip_runtime.h>
#include <hip/hip_bf16.h>
#include <hip/hip_fp16.h>
#include <cstdint>
#include <cstddef>

// ---------------------------------------------------------------------------
// FeatureExtractorGAT, round 28.
// Single change vs R27 (164 us; gat1_agg_h 46 us @ VALU 70% / occ 61%, only
// kernel above the harness poison fills):
//   Edge-phase gather tables PACKED: pxa[n][16] floats = {x[n][0..3],
//   a_s1[n][0..7], pad[4]} (64B row = one cache line). The per-edge float4
//   x-load + a_s1 scalar now hit the SAME line -> TA/L1 line-transactions
//   on the gather path halved; second load is an L1 hit by construction.
//   Table 2.4 -> 3.2 MB (still L2-resident). Identical arithmetic.
// Everything else byte-identical to R27.
// ---------------------------------------------------------------------------

typedef _Float16 half8 __attribute__((ext_vector_type(8)));
typedef float floatx4 __attribute__((ext_vector_type(4)));

constexpr int BSH = 7;            // 128 nodes per bucket
constexpr int MAXBUK = 512;       // supports N <= 65536

__global__ void zero_bcnt(int* __restrict__ bcnt)
{
    bcnt[threadIdx.x] = 0;        // MAXBUK = 512 = blockDim
}

// ---- fused setup: block 0 = prep(w1t,wa2t); [1,1+NW2T) = w2t;
// [A1_0, A1_0+NA1) = a1 (self-computed wa1 in LDS; writes packed pxa + a_d1);
// [H0, ...) = bucket_hist.
__global__ __launch_bounds__(256) void setup_kernel(
    const float* __restrict__ W1,
    const float* __restrict__ as1, const float* __restrict__ ad1,
    const float* __restrict__ W2,
    const float* __restrict__ as2, const float* __restrict__ ad2,
    const float* __restrict__ x, const int* __restrict__ ei,
    int E, int N,
    float4* __restrict__ w1t, float2* __restrict__ wa2t,
    __half* __restrict__ w2t,
    float* __restrict__ pxa, float* __restrict__ a_d1,
    int* __restrict__ bcnt,
    int NW2T, int NA1)
{
    __shared__ int   lcnt[MAXBUK];
    __shared__ float wa1s[64];
    int b = blockIdx.x;
    int t = threadIdx.x;
    int A1_0 = 1 + NW2T;
    int H0   = A1_0 + NA1;

    if (b == 0) {
        for (int i = t; i < 480; i += 256) {
            float accs = 0.f, accd = 0.f;
            #pragma unroll 4
            for (int c = 0; c < 96; ++c) {
                float w = W2[i * 96 + c];
                accs += w * as2[c];
                accd += w * ad2[c];
            }
            wa2t[i] = make_float2(accs, accd);
            w1t[i]  = make_float4(W1[i], W1[480 + i], W1[960 + i], W1[1440 + i]);
        }
    } else if (b < A1_0) {
        int idx = (b - 1) * 256 + t;
        if (idx < 96 * 480) {
            int n = idx / 480, k = idx - n * 480;
            w2t[idx] = __float2half(W2[k * 96 + n]);
        }
    } else if (b < H0) {
        if (t < 32) {
            int k = t >> 3, h = t & 7;
            float accs = 0.f, accd = 0.f;
            for (int c = 0; c < 60; ++c) {
                float w = W1[k * 480 + h * 60 + c];
                accs += w * as1[h * 60 + c];
                accd += w * ad1[h * 60 + c];
            }
            wa1s[k * 8 + h]      = accs;
            wa1s[32 + k * 8 + h] = accd;
        }
        __syncthreads();
        int n = (b - A1_0) * 256 + t;
        if (n < N) {
            float4 xv = *(const float4*)(x + (size_t)n * 4);
            float* pr = pxa + (size_t)n * 16;
            *(float4*)pr = xv;                       // cols 0..3: x row
            #pragma unroll
            for (int h = 0; h < 8; ++h) {
                float as = xv.x * wa1s[h] + xv.y * wa1s[8 + h]
                         + xv.z * wa1s[16 + h] + xv.w * wa1s[24 + h];
                float ad = xv.x * wa1s[32 + h] + xv.y * wa1s[40 + h]
                         + xv.z * wa1s[48 + h] + xv.w * wa1s[56 + h];
                pr[4 + h] = as;                      // cols 4..11: a_s1 row
                a_d1[n * 8 + h] = ad;
            }
        }
    } else {
        int nbuk = (N + 127) >> BSH;
        for (int i = t; i < nbuk; i += 256) lcnt[i] = 0;
        __syncthreads();
        #pragma unroll
        for (int u = 0; u < 8; ++u) {
            int e = (b - H0) * 2048 + u * 256 + t;
            if (e < E + N) {
                int d = (e < E) ? ei[E + e] : (e - E);
                atomicAdd(&lcnt[d >> BSH], 1);
            }
        }
        __syncthreads();
        for (int i = t; i < nbuk; i += 256)
            if (lcnt[i]) atomicAdd(&bcnt[i], lcnt[i]);
    }
}

// ---- CSR build pass 2: scan bucket counts (1 block, 512 thr)
__global__ __launch_bounds__(512) void bucket_scan(const int* __restrict__ bcnt, int nbuk,
                                                   int* __restrict__ boff,
                                                   int* __restrict__ bcursor,
                                                   int* __restrict__ row_ptr, int N)
{
    __shared__ int wsum[8];
    int t = threadIdx.x, lane = t & 63, wid = t >> 6;
    int v = (t < nbuk) ? bcnt[t] : 0;
    int x = v;
    #pragma unroll
    for (int off = 1; off < 64; off <<= 1) {
        int y = __shfl_up(x, off, 64);
        if (lane >= off) x += y;
    }
    if (lane == 63) wsum[wid] = x;
    __syncthreads();
    if (wid == 0) {
        int wv = (lane < 8) ? wsum[lane] : 0;
        #pragma unroll
        for (int off = 1; off < 8; off <<= 1) {
            int y = __shfl_up(wv, off, 64);
            if (lane >= off) wv += y;
        }
        if (lane < 8) wsum[lane] = wv;
    }
    __syncthreads();
    int excl = (wid ? wsum[wid - 1] : 0) + x - v;
    if (t < nbuk) { boff[t] = excl; bcursor[t] = excl; }
    if (t == nbuk - 1) { boff[nbuk] = excl + v; row_ptr[N] = excl + v; }
}

// ---- CSR build pass 3: multisplit (src,dst) pairs into bucket regions.
__global__ __launch_bounds__(256) void multisplit(const int* __restrict__ ei, int E, int N,
                                                  int* __restrict__ bcursor,
                                                  int2* __restrict__ ebuf)
{
    __shared__ int lcnt[MAXBUK];
    __shared__ int lbase[MAXBUK];
    int t = threadIdx.x;
    int nbuk = (N + 127) >> BSH;
    for (int b = t; b < nbuk; b += 256) lcnt[b] = 0;
    __syncthreads();
    constexpr int U = 16;
    int ss[U], dd[U], rk[U];
    bool ok[U];
    #pragma unroll
    for (int u = 0; u < U; ++u) {
        int e = blockIdx.x * (256 * U) + u * 256 + t;
        ok[u] = e < E + N;
        if (ok[u]) {
            if (e < E) { ss[u] = ei[e]; dd[u] = ei[E + e]; } else { ss[u] = dd[u] = e - E; }
            rk[u] = atomicAdd(&lcnt[dd[u] >> BSH], 1);
        }
    }
    __syncthreads();
    for (int b = t; b < nbuk; b += 256)
        lbase[b] = lcnt[b] ? atomicAdd(&bcursor[b], lcnt[b]) : 0;
    __syncthreads();
    #pragma unroll
    for (int u = 0; u < U; ++u)
        if (ok[u]) ebuf[(size_t)lbase[dd[u] >> BSH] + rk[u]] = make_int2(ss[u], dd[u]);
}

// ---- CSR build pass 4: one block per bucket; cursors in LDS; writes
// csr AND csrdst (dst companion, needed by the p2 phase).
__global__ __launch_bounds__(256) void csrfill2(const int2* __restrict__ ebuf,
                                                const int* __restrict__ boff,
                                                int* __restrict__ row_ptr,
                                                int* __restrict__ csr,
                                                int* __restrict__ csrdst, int N)
{
    int b = blockIdx.x;
    int node0 = b << BSH;
    int nnode = N - node0;  if (nnode > 128) nnode = 128;
    int beg = boff[b], end = boff[b + 1];
    __shared__ int hcnt[128], hcur[128];
    __shared__ int wends[4];
    int t = threadIdx.x;
    if (t < 128) hcnt[t] = 0;
    __syncthreads();
    for (int i = beg + t; i < end; i += 256)
        atomicAdd(&hcnt[ebuf[i].y - node0], 1);
    __syncthreads();
    int lane = t & 63, wid = t >> 6;
    int v = (t < 128) ? hcnt[t] : 0;
    int x = v;
    #pragma unroll
    for (int off = 1; off < 64; off <<= 1) {
        int y = __shfl_up(x, off, 64);
        if (lane >= off) x += y;
    }
    if (lane == 63) wends[wid] = x;
    __syncthreads();
    int excl = x - v + ((wid == 1) ? wends[0] : 0);
    if (t < 128) {
        hcur[t] = excl;
        if (t < nnode) row_ptr[node0 + t] = beg + excl;
    }
    __syncthreads();
    for (int i = beg + t; i < end; i += 256) {
        int2 e = ebuf[i];
        int p = atomicAdd(&hcur[e.y - node0], 1);
        csr[(size_t)beg + p]    = e.x;
        csrdst[(size_t)beg + p] = e.y;
    }
}

// ---- GAT layer 1: aggregation + h-phase, fused (1 node/wave).
// Edge phase: lane = es*8 + h, gathers from PACKED pxa (x + a_s1 in one
// 64B line per src). h-phase: lane l<60 handles cols h*60+l.
__global__ __launch_bounds__(256) void gat1_agg_h(
    const int* __restrict__ row_ptr, const int* __restrict__ csr,
    const float* __restrict__ pxa, const float* __restrict__ a_d1,
    const float4* __restrict__ w1t, const float* __restrict__ b1,
    const float2* __restrict__ wa2t,
    __half* __restrict__ h2buf, float* __restrict__ a2s, float* __restrict__ a2d, int N)
{
    __shared__ float4 w1s[480];
    __shared__ float2 wa2s[480];
    __shared__ float  b1s[480];
    __shared__ float  aggL[4][32];
    __shared__ float  ssumL[4][8];
    int t = threadIdx.x;
    for (int i = t; i < 480; i += 256) {
        w1s[i]  = w1t[i];
        wa2s[i] = wa2t[i];
        b1s[i]  = b1[i];
    }
    __syncthreads();   // tables ready

    int wv   = t >> 6;
    int node = blockIdx.x * 4 + wv;
    if (node >= N) return;
    int lane = t & 63;

    // ---- edge phase: lane = es*8 + h ----
    {
        int es = lane >> 3;
        int h  = lane & 7;
        float adh = a_d1[(size_t)node * 8 + h];
        float ax = 0.f, ay = 0.f, az = 0.f, aw = 0.f, sv = 0.f;
        int beg = row_ptr[node], end = row_ptr[node + 1];
        constexpr int U = 2;                 // 16 edges per iteration
        for (int base = beg; base < end; base += 8 * U) {
            int   src[U];
            float msk[U];
            #pragma unroll
            for (int u = 0; u < U; ++u) {
                int tt = base + u * 8 + es;
                msk[u] = (tt < end) ? 1.f : 0.f;
                src[u] = csr[tt < end ? tt : (end - 1)];
            }
            float4 xv[U];
            float  asv[U];
            #pragma unroll
            for (int u = 0; u < U; ++u) {
                const float* pr = pxa + (size_t)src[u] * 16;
                xv[u]  = *(const float4*)pr;     // same 64B line...
                asv[u] = pr[4 + h];              // ...as this scalar
            }
            #pragma unroll
            for (int u = 0; u < U; ++u) {
                float ev = asv[u] + adh;
                ev = fmaxf(ev, 0.2f * ev);
                float p = __expf(ev) * msk[u];
                sv += p;
                ax += p * xv[u].x;
                ay += p * xv[u].y;
                az += p * xv[u].z;
                aw += p * xv[u].w;
            }
        }
        #pragma unroll
        for (int off = 8; off <= 32; off <<= 1) {
            ax += __shfl_xor(ax, off);
            ay += __shfl_xor(ay, off);
            az += __shfl_xor(az, off);
            aw += __shfl_xor(aw, off);
            sv += __shfl_xor(sv, off);
        }
        if (lane < 8) {                       // es == 0 holds the totals
            aggL[wv][h * 4 + 0] = ax;
            aggL[wv][h * 4 + 1] = ay;
            aggL[wv][h * 4 + 2] = az;
            aggL[wv][h * 4 + 3] = aw;
            ssumL[wv][h] = sv;
        }
    }
    // same-wave LDS write->read: ordered by lgkmcnt, no barrier needed

    // ---- h phase ----
    bool act = lane < 60;
    float psrc = 0.f, pdst = 0.f;
    #pragma unroll
    for (int h = 0; h < 8; ++h) {
        float ag0 = aggL[wv][h * 4 + 0];
        float ag1 = aggL[wv][h * 4 + 1];
        float ag2 = aggL[wv][h * 4 + 2];
        float ag3 = aggL[wv][h * 4 + 3];
        float inv = 1.f / (ssumL[wv][h] + 1e-16f);
        if (act) {
            int col = h * 60 + lane;
            float4 w  = w1s[col];
            float raw = ag0 * w.x + ag1 * w.y + ag2 * w.z + ag3 * w.w;
            float v   = raw * inv + b1s[col];
            float o   = v > 0.f ? v : (__expf(v) - 1.f);
            h2buf[(size_t)node * 480 + col] = __float2half(o);
            float2 wz = wa2s[col];
            psrc += o * wz.x;
            pdst += o * wz.y;
        }
    }
    #pragma unroll
    for (int off = 32; off; off >>= 1) {
        psrc += __shfl_xor(psrc, off);
        pdst += __shfl_xor(pdst, off);
    }
    if (lane == 0) { a2s[node] = psrc; a2d[node] = pdst; }
}

// ---- tail: blockIdx < NG2 -> gemm2_mfma body; else -> p2 body.
__global__ __launch_bounds__(256) void tail_kernel(
    const __half* __restrict__ h2, const __half* __restrict__ w2t,
    __half* __restrict__ xh2h,
    const int* __restrict__ csr, const int* __restrict__ csrdst,
    const float* __restrict__ a_s2, const float* __restrict__ a_d2,
    float* __restrict__ pbuf2, int N, int EP, int NG2)
{
    if ((int)blockIdx.x < NG2) {
        // ---- gemm2: xh2h[N,96] = h2[N,480] @ W2t via MFMA fp16 (f32 accum)
        int wave = threadIdx.x >> 6;
        int lane = threadIdx.x & 63;
        int m0 = blockIdx.x * 64 + wave * 16;
        int ra   = lane & 15;
        int kgrp = lane >> 4;
        int m = m0 + ra;  if (m > N - 1) m = N - 1;   // clamp

        floatx4 acc[6];
        #pragma unroll
        for (int n = 0; n < 6; ++n) acc[n] = (floatx4){0.f, 0.f, 0.f, 0.f};

        const _Float16* arow = (const _Float16*)(h2 + (size_t)m * 480);
        const _Float16* wt   = (const _Float16*)w2t;
        for (int k0 = 0; k0 < 480; k0 += 32) {
            half8 af = *(const half8*)(arow + k0 + kgrp * 8);
            #pragma unroll
            for (int n = 0; n < 6; ++n) {
                half8 bf = *(const half8*)(wt + (size_t)(n * 16 + ra) * 480 + k0 + kgrp * 8);
                acc[n] = __builtin_amdgcn_mfma_f32_16x16x32_f16(af, bf, acc[n], 0, 0, 0);
            }
        }
        #pragma unroll
        for (int n = 0; n < 6; ++n) {
            int c = n * 16 + ra;
            #pragma unroll
            for (int j = 0; j < 4; ++j) {
                int r = m0 + kgrp * 4 + j;
                if (r < N) xh2h[(size_t)r * 96 + c] = __float2half(acc[n][j]);
            }
        }
    } else {
        // ---- p2: p[e] = exp(leaky(a_s2[csr[e]] + a_d2[csrdst[e]]))
        int i = ((blockIdx.x - NG2) * 256 + threadIdx.x) * 4;
        if (i + 3 < EP) {
            int4 s4 = *(const int4*)(csr + i);
            int4 d4 = *(const int4*)(csrdst + i);
            float e0 = a_s2[s4.x] + a_d2[d4.x];
            float e1 = a_s2[s4.y] + a_d2[d4.y];
            float e2 = a_s2[s4.z] + a_d2[d4.z];
            float e3 = a_s2[s4.w] + a_d2[d4.w];
            float4 o;
            o.x = __expf(fmaxf(e0, 0.2f * e0));
            o.y = __expf(fmaxf(e1, 0.2f * e1));
            o.z = __expf(fmaxf(e2, 0.2f * e2));
            o.w = __expf(fmaxf(e3, 0.2f * e3));
            *(float4*)(pbuf2 + i) = o;
        } else {
            for (int u = 0; u < 4; ++u) {
                int e = i + u;
                if (e < EP) {
                    float ev = a_s2[csr[e]] + a_d2[csrdst[e]];
                    pbuf2[e] = __expf(fmaxf(ev, 0.2f * ev));
                }
            }
        }
    }
}

// ---- GAT layer 2: wave/node; contiguous s_load batches of csr + pbuf2
// (independent), gather + cvt + 2 FMA per edge; U=16.
__global__ __launch_bounds__(256) void gat2_fused(
    const int* __restrict__ row_ptr, const int* __restrict__ csr,
    const float* __restrict__ pbuf2,
    const __half* __restrict__ xh2h, const float* __restrict__ b2,
    float* __restrict__ out, int N)
{
    int gid = blockIdx.x * blockDim.x + threadIdx.x;
    int node = gid >> 6;
    if (node >= N) return;
    int lane = threadIdx.x & 63;
    bool act = lane < 48;
    float s = 0.f, ax = 0.f, ay = 0.f;
    int beg = __builtin_amdgcn_readfirstlane(row_ptr[node]);
    int end = __builtin_amdgcn_readfirstlane(row_ptr[node + 1]);
    constexpr int U = 16;
    for (int e0 = beg; e0 < end; e0 += U) {
        int   srcs[U];
        float pv[U];
        #pragma unroll
        for (int u = 0; u < U; ++u) {
            int t = e0 + u;  if (t > end - 1) t = end - 1;      // scalar clamp
            srcs[u] = __builtin_amdgcn_readfirstlane(csr[t]);
            float pr = __uint_as_float(
                __builtin_amdgcn_readfirstlane(__float_as_uint(pbuf2[t])));
            pv[u] = (e0 + u < end) ? pr : 0.f;                  // uniform select
        }
        __half2 gv[U];
        if (act) {
            #pragma unroll
            for (int u = 0; u < U; ++u)
                gv[u] = ((const __half2*)(xh2h + (size_t)srcs[u] * 96))[lane];
        }
        #pragma unroll
        for (int u = 0; u < U; ++u) {
            s += pv[u];
            if (act) {
                float2 fg = __half22float2(gv[u]);
                ax += pv[u] * fg.x;
                ay += pv[u] * fg.y;
            }
        }
    }
    float inv = 1.f / (s + 1e-16f);
    if (act) {
        out[(size_t)node * 96 + 2 * lane]     = ax * inv + b2[2 * lane];
        out[(size_t)node * 96 + 2 * lane + 1] = ay * inv + b2[2 * lane + 1];
    }
}

extern "C" void kernel_launch(void* const* d_in, const int* in_sizes, int n_in,
                              void* d_out, int out_size, void* d_ws, size_t ws_size,
                              hipStream_t stream)
{
    const float* x   = (const float*)d_in[0];
    const int*   ei  = (const int*)  d_in[1];
    const float* W1  = (const float*)d_in[2];
    const float* as1 = (const float*)d_in[3];
    const float* ad1 = (const float*)d_in[4];
    const float* b1  = (const float*)d_in[5];
    const float* W2  = (const float*)d_in[6];
    const float* as2 = (const float*)d_in[7];
    const float* ad2 = (const float*)d_in[8];
    const float* b2  = (const float*)d_in[9];
    float* out = (float*)d_out;

    int N  = in_sizes[0] / 4;   // 50000
    int E  = in_sizes[1] / 2;   // 800000
    int EP = E + N;
    int NBUK  = (N + 127) >> BSH;           // 391
    int NW2T  = (96 * 480 + 255) / 256;     // 180
    int NA1   = (N + 255) / 256;            // 196
    int NBK_H = (EP + 2047) / 2048;         // 416
    int NBK_M = (EP + 4095) / 4096;         // multisplit blocks (U=16)
    int NSETUP = 1 + NW2T + NA1 + NBK_H;
    int NG2   = (N + 63) / 64;              // gemm2 blocks
    int NP2   = (EP + 1023) / 1024;         // p2 blocks

    float* f = (float*)d_ws;
    float* pxa   = f;  f += (size_t)N * 16;   // packed {x[4], a_s1[8], pad[4]}
    float* a_d1  = f;  f += (size_t)N * 8;
    float* a_s2  = f;  f += N;
    float* a_d2  = f;  f += N;
    float4* w1t  = (float4*)f;  f += 480 * 4;
    float2* wa2t = (float2*)f;  f += 480 * 2;
    __half* h2buf = (__half*)f;
    __half* hp   = h2buf + (size_t)N * 480;
    __half* xh2h = hp;   hp += (size_t)N * 96;
    __half* w2t  = hp;   hp += 96 * 480;
    int2* ebuf   = (int2*)hp;
    int* ip      = (int*)(ebuf + EP);
    int* row_ptr = ip;  ip += N + 1;
    int* bcnt    = ip;  ip += MAXBUK;
    int* boff    = ip;  ip += MAXBUK + 1;
    int* bcursor = ip;  ip += MAXBUK;
    int* csr     = ip;  ip += EP;
    int* csrdst  = ip;  ip += EP;
    float* pbuf2 = (float*)ip;  ip += EP;

    size_t needed = (size_t)((char*)ip - (char*)d_ws);
    if (needed > ws_size) return;  // loud failure if scratch too small

    zero_bcnt<<<1, MAXBUK, 0, stream>>>(bcnt);
    setup_kernel<<<NSETUP, 256, 0, stream>>>(
        W1, as1, ad1, W2, as2, ad2, x, ei, E, N,
        w1t, wa2t, w2t, pxa, a_d1, bcnt, NW2T, NA1);
    bucket_scan<<<1, 512, 0, stream>>>(bcnt, NBUK, boff, bcursor, row_ptr, N);
    multisplit<<<NBK_M, 256, 0, stream>>>(ei, E, N, bcursor, ebuf);
    csrfill2<<<NBUK, 256, 0, stream>>>(ebuf, boff, row_ptr, csr, csrdst, N);
    gat1_agg_h<<<(N + 3) / 4, 256, 0, stream>>>(
        row_ptr, csr, pxa, a_d1, w1t, b1, wa2t, h2buf, a_s2, a_d2, N);
    tail_kernel<<<NG2 + NP2, 256, 0, stream>>>(
        h2buf, w2t, xh2h, csr, csrdst, a_s2, a_d2, pbuf2, N, EP, NG2);
    gat2_fused<<<(N * 64 + 255) / 256, 256, 0, stream>>>(
        row_ptr, csr, pbuf2, xh2h, b2, out, N);
}

// Round 29
// 160.054 us; speedup vs baseline: 1.0528x; 1.0156x over previous
//
#include <hip/hip_runtime.h>
#include <hip/hip_bf16.h>
#include <hip/hip_fp16.h>
#include <cstdint>
#include <cstddef>

// ---------------------------------------------------------------------------
// FeatureExtractorGAT, round 29.
// Single change vs R28 (162.5 us; gat1_agg_h flat at 46 us -> line-packing
// refuted, kernel is VALU-op bound on non-gather work; IEEE divide in the
// h-phase costs ~8 VALU ops x 8 heads x 60 lanes per node):
//   Softmax divisions -> __builtin_amdgcn_rcpf (v_rcp_f32, ~1 ulp):
//   gat1_agg_h h-phase inv and gat2_fused inv. absmax tolerance (2e-3)
//   is 4 orders above rcp error.
// Everything else byte-identical to R28 (packed pxa kept: neutral but
// harmless, avoids another variable).
// ---------------------------------------------------------------------------

typedef _Float16 half8 __attribute__((ext_vector_type(8)));
typedef float floatx4 __attribute__((ext_vector_type(4)));

constexpr int BSH = 7;            // 128 nodes per bucket
constexpr int MAXBUK = 512;       // supports N <= 65536

__global__ void zero_bcnt(int* __restrict__ bcnt)
{
    bcnt[threadIdx.x] = 0;        // MAXBUK = 512 = blockDim
}

// ---- fused setup: block 0 = prep(w1t,wa2t); [1,1+NW2T) = w2t;
// [A1_0, A1_0+NA1) = a1 (self-computed wa1 in LDS; writes packed pxa + a_d1);
// [H0, ...) = bucket_hist.
__global__ __launch_bounds__(256) void setup_kernel(
    const float* __restrict__ W1,
    const float* __restrict__ as1, const float* __restrict__ ad1,
    const float* __restrict__ W2,
    const float* __restrict__ as2, const float* __restrict__ ad2,
    const float* __restrict__ x, const int* __restrict__ ei,
    int E, int N,
    float4* __restrict__ w1t, float2* __restrict__ wa2t,
    __half* __restrict__ w2t,
    float* __restrict__ pxa, float* __restrict__ a_d1,
    int* __restrict__ bcnt,
    int NW2T, int NA1)
{
    __shared__ int   lcnt[MAXBUK];
    __shared__ float wa1s[64];
    int b = blockIdx.x;
    int t = threadIdx.x;
    int A1_0 = 1 + NW2T;
    int H0   = A1_0 + NA1;

    if (b == 0) {
        for (int i = t; i < 480; i += 256) {
            float accs = 0.f, accd = 0.f;
            #pragma unroll 4
            for (int c = 0; c < 96; ++c) {
                float w = W2[i * 96 + c];
                accs += w * as2[c];
                accd += w * ad2[c];
            }
            wa2t[i] = make_float2(accs, accd);
            w1t[i]  = make_float4(W1[i], W1[480 + i], W1[960 + i], W1[1440 + i]);
        }
    } else if (b < A1_0) {
        int idx = (b - 1) * 256 + t;
        if (idx < 96 * 480) {
            int n = idx / 480, k = idx - n * 480;
            w2t[idx] = __float2half(W2[k * 96 + n]);
        }
    } else if (b < H0) {
        if (t < 32) {
            int k = t >> 3, h = t & 7;
            float accs = 0.f, accd = 0.f;
            for (int c = 0; c < 60; ++c) {
                float w = W1[k * 480 + h * 60 + c];
                accs += w * as1[h * 60 + c];
                accd += w * ad1[h * 60 + c];
            }
            wa1s[k * 8 + h]      = accs;
            wa1s[32 + k * 8 + h] = accd;
        }
        __syncthreads();
        int n = (b - A1_0) * 256 + t;
        if (n < N) {
            float4 xv = *(const float4*)(x + (size_t)n * 4);
            float* pr = pxa + (size_t)n * 16;
            *(float4*)pr = xv;                       // cols 0..3: x row
            #pragma unroll
            for (int h = 0; h < 8; ++h) {
                float as = xv.x * wa1s[h] + xv.y * wa1s[8 + h]
                         + xv.z * wa1s[16 + h] + xv.w * wa1s[24 + h];
                float ad = xv.x * wa1s[32 + h] + xv.y * wa1s[40 + h]
                         + xv.z * wa1s[48 + h] + xv.w * wa1s[56 + h];
                pr[4 + h] = as;                      // cols 4..11: a_s1 row
                a_d1[n * 8 + h] = ad;
            }
        }
    } else {
        int nbuk = (N + 127) >> BSH;
        for (int i = t; i < nbuk; i += 256) lcnt[i] = 0;
        __syncthreads();
        #pragma unroll
        for (int u = 0; u < 8; ++u) {
            int e = (b - H0) * 2048 + u * 256 + t;
            if (e < E + N) {
                int d = (e < E) ? ei[E + e] : (e - E);
                atomicAdd(&lcnt[d >> BSH], 1);
            }
        }
        __syncthreads();
        for (int i = t; i < nbuk; i += 256)
            if (lcnt[i]) atomicAdd(&bcnt[i], lcnt[i]);
    }
}

// ---- CSR build pass 2: scan bucket counts (1 block, 512 thr)
__global__ __launch_bounds__(512) void bucket_scan(const int* __restrict__ bcnt, int nbuk,
                                                   int* __restrict__ boff,
                                                   int* __restrict__ bcursor,
                                                   int* __restrict__ row_ptr, int N)
{
    __shared__ int wsum[8];
    int t = threadIdx.x, lane = t & 63, wid = t >> 6;
    int v = (t < nbuk) ? bcnt[t] : 0;
    int x = v;
    #pragma unroll
    for (int off = 1; off < 64; off <<= 1) {
        int y = __shfl_up(x, off, 64);
        if (lane >= off) x += y;
    }
    if (lane == 63) wsum[wid] = x;
    __syncthreads();
    if (wid == 0) {
        int wv = (lane < 8) ? wsum[lane] : 0;
        #pragma unroll
        for (int off = 1; off < 8; off <<= 1) {
            int y = __shfl_up(wv, off, 64);
            if (lane >= off) wv += y;
        }
        if (lane < 8) wsum[lane] = wv;
    }
    __syncthreads();
    int excl = (wid ? wsum[wid - 1] : 0) + x - v;
    if (t < nbuk) { boff[t] = excl; bcursor[t] = excl; }
    if (t == nbuk - 1) { boff[nbuk] = excl + v; row_ptr[N] = excl + v; }
}

// ---- CSR build pass 3: multisplit (src,dst) pairs into bucket regions.
__global__ __launch_bounds__(256) void multisplit(const int* __restrict__ ei, int E, int N,
                                                  int* __restrict__ bcursor,
                                                  int2* __restrict__ ebuf)
{
    __shared__ int lcnt[MAXBUK];
    __shared__ int lbase[MAXBUK];
    int t = threadIdx.x;
    int nbuk = (N + 127) >> BSH;
    for (int b = t; b < nbuk; b += 256) lcnt[b] = 0;
    __syncthreads();
    constexpr int U = 16;
    int ss[U], dd[U], rk[U];
    bool ok[U];
    #pragma unroll
    for (int u = 0; u < U; ++u) {
        int e = blockIdx.x * (256 * U) + u * 256 + t;
        ok[u] = e < E + N;
        if (ok[u]) {
            if (e < E) { ss[u] = ei[e]; dd[u] = ei[E + e]; } else { ss[u] = dd[u] = e - E; }
            rk[u] = atomicAdd(&lcnt[dd[u] >> BSH], 1);
        }
    }
    __syncthreads();
    for (int b = t; b < nbuk; b += 256)
        lbase[b] = lcnt[b] ? atomicAdd(&bcursor[b], lcnt[b]) : 0;
    __syncthreads();
    #pragma unroll
    for (int u = 0; u < U; ++u)
        if (ok[u]) ebuf[(size_t)lbase[dd[u] >> BSH] + rk[u]] = make_int2(ss[u], dd[u]);
}

// ---- CSR build pass 4: one block per bucket; cursors in LDS; writes
// csr AND csrdst (dst companion, needed by the p2 phase).
__global__ __launch_bounds__(256) void csrfill2(const int2* __restrict__ ebuf,
                                                const int* __restrict__ boff,
                                                int* __restrict__ row_ptr,
                                                int* __restrict__ csr,
                                                int* __restrict__ csrdst, int N)
{
    int b = blockIdx.x;
    int node0 = b << BSH;
    int nnode = N - node0;  if (nnode > 128) nnode = 128;
    int beg = boff[b], end = boff[b + 1];
    __shared__ int hcnt[128], hcur[128];
    __shared__ int wends[4];
    int t = threadIdx.x;
    if (t < 128) hcnt[t] = 0;
    __syncthreads();
    for (int i = beg + t; i < end; i += 256)
        atomicAdd(&hcnt[ebuf[i].y - node0], 1);
    __syncthreads();
    int lane = t & 63, wid = t >> 6;
    int v = (t < 128) ? hcnt[t] : 0;
    int x = v;
    #pragma unroll
    for (int off = 1; off < 64; off <<= 1) {
        int y = __shfl_up(x, off, 64);
        if (lane >= off) x += y;
    }
    if (lane == 63) wends[wid] = x;
    __syncthreads();
    int excl = x - v + ((wid == 1) ? wends[0] : 0);
    if (t < 128) {
        hcur[t] = excl;
        if (t < nnode) row_ptr[node0 + t] = beg + excl;
    }
    __syncthreads();
    for (int i = beg + t; i < end; i += 256) {
        int2 e = ebuf[i];
        int p = atomicAdd(&hcur[e.y - node0], 1);
        csr[(size_t)beg + p]    = e.x;
        csrdst[(size_t)beg + p] = e.y;
    }
}

// ---- GAT layer 1: aggregation + h-phase, fused (1 node/wave).
// Edge phase: lane = es*8 + h, gathers from PACKED pxa.
// h-phase: lane l<60 handles cols h*60+l; inv via v_rcp_f32.
__global__ __launch_bounds__(256) void gat1_agg_h(
    const int* __restrict__ row_ptr, const int* __restrict__ csr,
    const float* __restrict__ pxa, const float* __restrict__ a_d1,
    const float4* __restrict__ w1t, const float* __restrict__ b1,
    const float2* __restrict__ wa2t,
    __half* __restrict__ h2buf, float* __restrict__ a2s, float* __restrict__ a2d, int N)
{
    __shared__ float4 w1s[480];
    __shared__ float2 wa2s[480];
    __shared__ float  b1s[480];
    __shared__ float  aggL[4][32];
    __shared__ float  ssumL[4][8];
    int t = threadIdx.x;
    for (int i = t; i < 480; i += 256) {
        w1s[i]  = w1t[i];
        wa2s[i] = wa2t[i];
        b1s[i]  = b1[i];
    }
    __syncthreads();   // tables ready

    int wv   = t >> 6;
    int node = blockIdx.x * 4 + wv;
    if (node >= N) return;
    int lane = t & 63;

    // ---- edge phase: lane = es*8 + h ----
    {
        int es = lane >> 3;
        int h  = lane & 7;
        float adh = a_d1[(size_t)node * 8 + h];
        float ax = 0.f, ay = 0.f, az = 0.f, aw = 0.f, sv = 0.f;
        int beg = row_ptr[node], end = row_ptr[node + 1];
        constexpr int U = 2;                 // 16 edges per iteration
        for (int base = beg; base < end; base += 8 * U) {
            int   src[U];
            float msk[U];
            #pragma unroll
            for (int u = 0; u < U; ++u) {
                int tt = base + u * 8 + es;
                msk[u] = (tt < end) ? 1.f : 0.f;
                src[u] = csr[tt < end ? tt : (end - 1)];
            }
            float4 xv[U];
            float  asv[U];
            #pragma unroll
            for (int u = 0; u < U; ++u) {
                const float* pr = pxa + (size_t)src[u] * 16;
                xv[u]  = *(const float4*)pr;
                asv[u] = pr[4 + h];
            }
            #pragma unroll
            for (int u = 0; u < U; ++u) {
                float ev = asv[u] + adh;
                ev = fmaxf(ev, 0.2f * ev);
                float p = __expf(ev) * msk[u];
                sv += p;
                ax += p * xv[u].x;
                ay += p * xv[u].y;
                az += p * xv[u].z;
                aw += p * xv[u].w;
            }
        }
        #pragma unroll
        for (int off = 8; off <= 32; off <<= 1) {
            ax += __shfl_xor(ax, off);
            ay += __shfl_xor(ay, off);
            az += __shfl_xor(az, off);
            aw += __shfl_xor(aw, off);
            sv += __shfl_xor(sv, off);
        }
        if (lane < 8) {                       // es == 0 holds the totals
            aggL[wv][h * 4 + 0] = ax;
            aggL[wv][h * 4 + 1] = ay;
            aggL[wv][h * 4 + 2] = az;
            aggL[wv][h * 4 + 3] = aw;
            ssumL[wv][h] = sv;
        }
    }
    // same-wave LDS write->read: ordered by lgkmcnt, no barrier needed

    // ---- h phase ----
    bool act = lane < 60;
    float psrc = 0.f, pdst = 0.f;
    #pragma unroll
    for (int h = 0; h < 8; ++h) {
        float ag0 = aggL[wv][h * 4 + 0];
        float ag1 = aggL[wv][h * 4 + 1];
        float ag2 = aggL[wv][h * 4 + 2];
        float ag3 = aggL[wv][h * 4 + 3];
        float inv = __builtin_amdgcn_rcpf(ssumL[wv][h] + 1e-16f);  // v_rcp_f32
        if (act) {
            int col = h * 60 + lane;
            float4 w  = w1s[col];
            float raw = ag0 * w.x + ag1 * w.y + ag2 * w.z + ag3 * w.w;
            float v   = raw * inv + b1s[col];
            float o   = v > 0.f ? v : (__expf(v) - 1.f);
            h2buf[(size_t)node * 480 + col] = __float2half(o);
            float2 wz = wa2s[col];
            psrc += o * wz.x;
            pdst += o * wz.y;
        }
    }
    #pragma unroll
    for (int off = 32; off; off >>= 1) {
        psrc += __shfl_xor(psrc, off);
        pdst += __shfl_xor(pdst, off);
    }
    if (lane == 0) { a2s[node] = psrc; a2d[node] = pdst; }
}

// ---- tail: blockIdx < NG2 -> gemm2_mfma body; else -> p2 body.
__global__ __launch_bounds__(256) void tail_kernel(
    const __half* __restrict__ h2, const __half* __restrict__ w2t,
    __half* __restrict__ xh2h,
    const int* __restrict__ csr, const int* __restrict__ csrdst,
    const float* __restrict__ a_s2, const float* __restrict__ a_d2,
    float* __restrict__ pbuf2, int N, int EP, int NG2)
{
    if ((int)blockIdx.x < NG2) {
        // ---- gemm2: xh2h[N,96] = h2[N,480] @ W2t via MFMA fp16 (f32 accum)
        int wave = threadIdx.x >> 6;
        int lane = threadIdx.x & 63;
        int m0 = blockIdx.x * 64 + wave * 16;
        int ra   = lane & 15;
        int kgrp = lane >> 4;
        int m = m0 + ra;  if (m > N - 1) m = N - 1;   // clamp

        floatx4 acc[6];
        #pragma unroll
        for (int n = 0; n < 6; ++n) acc[n] = (floatx4){0.f, 0.f, 0.f, 0.f};

        const _Float16* arow = (const _Float16*)(h2 + (size_t)m * 480);
        const _Float16* wt   = (const _Float16*)w2t;
        for (int k0 = 0; k0 < 480; k0 += 32) {
            half8 af = *(const half8*)(arow + k0 + kgrp * 8);
            #pragma unroll
            for (int n = 0; n < 6; ++n) {
                half8 bf = *(const half8*)(wt + (size_t)(n * 16 + ra) * 480 + k0 + kgrp * 8);
                acc[n] = __builtin_amdgcn_mfma_f32_16x16x32_f16(af, bf, acc[n], 0, 0, 0);
            }
        }
        #pragma unroll
        for (int n = 0; n < 6; ++n) {
            int c = n * 16 + ra;
            #pragma unroll
            for (int j = 0; j < 4; ++j) {
                int r = m0 + kgrp * 4 + j;
                if (r < N) xh2h[(size_t)r * 96 + c] = __float2half(acc[n][j]);
            }
        }
    } else {
        // ---- p2: p[e] = exp(leaky(a_s2[csr[e]] + a_d2[csrdst[e]]))
        int i = ((blockIdx.x - NG2) * 256 + threadIdx.x) * 4;
        if (i + 3 < EP) {
            int4 s4 = *(const int4*)(csr + i);
            int4 d4 = *(const int4*)(csrdst + i);
            float e0 = a_s2[s4.x] + a_d2[d4.x];
            float e1 = a_s2[s4.y] + a_d2[d4.y];
            float e2 = a_s2[s4.z] + a_d2[d4.z];
            float e3 = a_s2[s4.w] + a_d2[d4.w];
            float4 o;
            o.x = __expf(fmaxf(e0, 0.2f * e0));
            o.y = __expf(fmaxf(e1, 0.2f * e1));
            o.z = __expf(fmaxf(e2, 0.2f * e2));
            o.w = __expf(fmaxf(e3, 0.2f * e3));
            *(float4*)(pbuf2 + i) = o;
        } else {
            for (int u = 0; u < 4; ++u) {
                int e = i + u;
                if (e < EP) {
                    float ev = a_s2[csr[e]] + a_d2[csrdst[e]];
                    pbuf2[e] = __expf(fmaxf(ev, 0.2f * ev));
                }
            }
        }
    }
}

// ---- GAT layer 2: wave/node; contiguous s_load batches of csr + pbuf2
// (independent), gather + cvt + 2 FMA per edge; U=16; inv via v_rcp_f32.
__global__ __launch_bounds__(256) void gat2_fused(
    const int* __restrict__ row_ptr, const int* __restrict__ csr,
    const float* __restrict__ pbuf2,
    const __half* __restrict__ xh2h, const float* __restrict__ b2,
    float* __restrict__ out, int N)
{
    int gid = blockIdx.x * blockDim.x + threadIdx.x;
    int node = gid >> 6;
    if (node >= N) return;
    int lane = threadIdx.x & 63;
    bool act = lane < 48;
    float s = 0.f, ax = 0.f, ay = 0.f;
    int beg = __builtin_amdgcn_readfirstlane(row_ptr[node]);
    int end = __builtin_amdgcn_readfirstlane(row_ptr[node + 1]);
    constexpr int U = 16;
    for (int e0 = beg; e0 < end; e0 += U) {
        int   srcs[U];
        float pv[U];
        #pragma unroll
        for (int u = 0; u < U; ++u) {
            int t = e0 + u;  if (t > end - 1) t = end - 1;      // scalar clamp
            srcs[u] = __builtin_amdgcn_readfirstlane(csr[t]);
            float pr = __uint_as_float(
                __builtin_amdgcn_readfirstlane(__float_as_uint(pbuf2[t])));
            pv[u] = (e0 + u < end) ? pr : 0.f;                  // uniform select
        }
        __half2 gv[U];
        if (act) {
            #pragma unroll
            for (int u = 0; u < U; ++u)
                gv[u] = ((const __half2*)(xh2h + (size_t)srcs[u] * 96))[lane];
        }
        #pragma unroll
        for (int u = 0; u < U; ++u) {
            s += pv[u];
            if (act) {
                float2 fg = __half22float2(gv[u]);
                ax += pv[u] * fg.x;
                ay += pv[u] * fg.y;
            }
        }
    }
    float inv = __builtin_amdgcn_rcpf(s + 1e-16f);   // v_rcp_f32
    if (act) {
        out[(size_t)node * 96 + 2 * lane]     = ax * inv + b2[2 * lane];
        out[(size_t)node * 96 + 2 * lane + 1] = ay * inv + b2[2 * lane + 1];
    }
}

extern "C" void kernel_launch(void* const* d_in, const int* in_sizes, int n_in,
                              void* d_out, int out_size, void* d_ws, size_t ws_size,
                              hipStream_t stream)
{
    const float* x   = (const float*)d_in[0];
    const int*   ei  = (const int*)  d_in[1];
    const float* W1  = (const float*)d_in[2];
    const float* as1 = (const float*)d_in[3];
    const float* ad1 = (const float*)d_in[4];
    const float* b1  = (const float*)d_in[5];
    const float* W2  = (const float*)d_in[6];
    const float* as2 = (const float*)d_in[7];
    const float* ad2 = (const float*)d_in[8];
    const float* b2  = (const float*)d_in[9];
    float* out = (float*)d_out;

    int N  = in_sizes[0] / 4;   // 50000
    int E  = in_sizes[1] / 2;   // 800000
    int EP = E + N;
    int NBUK  = (N + 127) >> BSH;           // 391
    int NW2T  = (96 * 480 + 255) / 256;     // 180
    int NA1   = (N + 255) / 256;            // 196
    int NBK_H = (EP + 2047) / 2048;         // 416
    int NBK_M = (EP + 4095) / 4096;         // multisplit blocks (U=16)
    int NSETUP = 1 + NW2T + NA1 + NBK_H;
    int NG2   = (N + 63) / 64;              // gemm2 blocks
    int NP2   = (EP + 1023) / 1024;         // p2 blocks

    float* f = (float*)d_ws;
    float* pxa   = f;  f += (size_t)N * 16;   // packed {x[4], a_s1[8], pad[4]}
    float* a_d1  = f;  f += (size_t)N * 8;
    float* a_s2  = f;  f += N;
    float* a_d2  = f;  f += N;
    float4* w1t  = (float4*)f;  f += 480 * 4;
    float2* wa2t = (float2*)f;  f += 480 * 2;
    __half* h2buf = (__half*)f;
    __half* hp   = h2buf + (size_t)N * 480;
    __half* xh2h = hp;   hp += (size_t)N * 96;
    __half* w2t  = hp;   hp += 96 * 480;
    int2* ebuf   = (int2*)hp;
    int* ip      = (int*)(ebuf + EP);
    int* row_ptr = ip;  ip += N + 1;
    int* bcnt    = ip;  ip += MAXBUK;
    int* boff    = ip;  ip += MAXBUK + 1;
    int* bcursor = ip;  ip += MAXBUK;
    int* csr     = ip;  ip += EP;
    int* csrdst  = ip;  ip += EP;
    float* pbuf2 = (float*)ip;  ip += EP;

    size_t needed = (size_t)((char*)ip - (char*)d_ws);
    if (needed > ws_size) return;  // loud failure if scratch too small

    zero_bcnt<<<1, MAXBUK, 0, stream>>>(bcnt);
    setup_kernel<<<NSETUP, 256, 0, stream>>>(
        W1, as1, ad1, W2, as2, ad2, x, ei, E, N,
        w1t, wa2t, w2t, pxa, a_d1, bcnt, NW2T, NA1);
    bucket_scan<<<1, 512, 0, stream>>>(bcnt, NBUK, boff, bcursor, row_ptr, N);
    multisplit<<<NBK_M, 256, 0, stream>>>(ei, E, N, bcursor, ebuf);
    csrfill2<<<NBUK, 256, 0, stream>>>(ebuf, boff, row_ptr, csr, csrdst, N);
    gat1_agg_h<<<(N + 3) / 4, 256, 0, stream>>>(
        row_ptr, csr, pxa, a_d1, w1t, b1, wa2t, h2buf, a_s2, a_d2, N);
    tail_kernel<<<NG2 + NP2, 256, 0, stream>>>(
        h2buf, w2t, xh2h, csr, csrdst, a_s2, a_d2, pbuf2, N, EP, NG2);
    gat2_fused<<<(N * 64 + 255) / 256, 256, 0, stream>>>(
        row_ptr, csr, pbuf2, xh2h, b2, out, N);
}